// Round 4
// baseline (60.261 us; speedup 1.0000x reference)
//
#include <hip/hip_runtime.h>

// Problem constants (match reference setup_inputs)
#define MM 100000            // frames
#define CC 24                // cameras
#define BLK 256              // 4 waves per block
#define WPB (BLK / 64)       // waves per block
#define GRID 1280            // persistent blocks (~5/CU)
#define NW (GRID * WPB)      // total waves = 5120
#define NP (MM / 2)          // frame-pairs = 50000 (each wave-iter does 2 frames)

// Per-(frame,camera) working set for one pipeline stage.
// qv: lanes cl<9 carry pole3d[m][cl]; broadcast later via ds_bpermute.
struct Pack { float2 a0, a1, a2; float w; float qv; };

__device__ __forceinline__ Pack load_pack(
    const float* __restrict__ pole3d, const float* __restrict__ pole2d,
    const int* __restrict__ mask, int m, int c, int cl, float active)
{
    Pack pk;
    const float2* pd = (const float2*)(pole2d + ((size_t)m * CC + c) * 6);
    pk.a0 = pd[0]; pk.a1 = pd[1]; pk.a2 = pd[2];
    pk.w  = active * (float)mask[(size_t)m * CC + c];
    float qv = 0.f;
    if (cl < 9) qv = pole3d[(size_t)m * 9 + cl];   // exec-masked, 1 VMEM inst
    pk.qv = qv;
    return pk;
}

__global__ __launch_bounds__(BLK) void ba_main_kernel(
    const float* __restrict__ pole3d,   // [M,3,3]
    const float* __restrict__ pole2d,   // [M,C,3,2]
    const float* __restrict__ Kmat,     // [C,3,3]
    const float* __restrict__ dist,     // [C,5]
    const float* __restrict__ Rmat,     // [C,3,3]
    const float* __restrict__ tvec,     // [C,3]
    const int*   __restrict__ mask,     // [M,C]
    float* __restrict__ ws,             // [0]:counter  [64..]:partials[GRID]
    float* __restrict__ out)
{
    const int tid  = threadIdx.x;
    const int lane = tid & 63;
    const int half = lane >> 5;               // which frame of the pair
    const int cl   = lane & 31;               // camera lane 0..31
    const int c    = (cl < CC) ? cl : (CC - 1);
    const float active = (cl < CC) ? 1.f : 0.f;
    const int qbase = half * 128;             // ds_bpermute byte base (lane half*32)

    // Per-lane camera parameters in registers (loaded once per block lifetime)
    const float fx = Kmat[c * 9 + 0], fy = Kmat[c * 9 + 4];
    const float u0 = Kmat[c * 9 + 2], v0 = Kmat[c * 9 + 5];
    const float k1 = dist[c * 5 + 0], k2 = dist[c * 5 + 1];
    const float p1 = dist[c * 5 + 2], p2 = dist[c * 5 + 3], k3 = dist[c * 5 + 4];
    const float r00 = Rmat[c * 9 + 0], r01 = Rmat[c * 9 + 1], r02 = Rmat[c * 9 + 2];
    const float r10 = Rmat[c * 9 + 3], r11 = Rmat[c * 9 + 4], r12 = Rmat[c * 9 + 5];
    const float r20 = Rmat[c * 9 + 6], r21 = Rmat[c * 9 + 7], r22 = Rmat[c * 9 + 8];
    const float t0 = tvec[c * 3 + 0], t1 = tvec[c * 3 + 1], t2 = tvec[c * 3 + 2];

    const int wid = blockIdx.x * WPB + (tid >> 6);   // global wave id

    float acc = 0.f;

    // Computes this half's frame loss from a Pack; adds into acc.
    auto consume = [&](const Pack& pk) {
        // Broadcast pole3d from lanes (half*32 + 0..8) to the whole half
        float q[9];
        #pragma unroll
        for (int i = 0; i < 9; ++i)
            q[i] = __int_as_float(__builtin_amdgcn_ds_bpermute(
                       qbase + 4 * i, __float_as_int(pk.qv)));
        const float2 obs[3] = {pk.a0, pk.a1, pk.a2};
        float s = 0.f;
        #pragma unroll
        for (int i = 0; i < 3; ++i) {
            const float X = q[3 * i + 0], Y = q[3 * i + 1], Z = q[3 * i + 2];
            const float xc = r00 * X + r01 * Y + r02 * Z + t0;
            const float yc = r10 * X + r11 * Y + r12 * Z + t1;
            const float zc = r20 * X + r21 * Y + r22 * Z + t2;
            const float inv = __builtin_amdgcn_rcpf(zc);
            const float x0 = xc * inv, x1 = yc * inv;
            const float r2 = x0 * x0 + x1 * x1;
            const float radial = 1.f + r2 * (k1 + r2 * (k2 + r2 * k3));
            const float xu = x0 * radial + 2.f * p1 * x0 * x1 + p2 * (r2 + 2.f * x0 * x0);
            const float yu = x1 * radial + p1 * (r2 + 2.f * x1 * x1) + 2.f * p2 * x0 * x1;
            const float u = fx * xu + u0;
            const float v = fy * yu + v0;
            const float dx = obs[i].x - u;
            const float dy = obs[i].y - v;
            s += __builtin_amdgcn_sqrtf(dx * dx + dy * dy);
        }
        s *= (1.f / 3.f);
        float ss = s * pk.w, ww = pk.w;
        #pragma unroll
        for (int d = 1; d < 32; d <<= 1) {       // stays within the 32-lane half
            ss += __shfl_xor(ss, d);
            ww += __shfl_xor(ww, d);
        }
        acc += ss * __builtin_amdgcn_rcpf(ww);   // ww in [1,24]
    };

    // Software pipeline: 2 frame-pairs in flight
    Pack c0 = load_pack(pole3d, pole2d, mask, 2 * wid + half, c, cl, active);
    Pack c1 = load_pack(pole3d, pole2d, mask, 2 * (wid + NW) + half, c, cl, active);

    for (int p = wid; p < NP; p += 2 * NW) {
        const int p2 = p + 2 * NW, p3 = p + 3 * NW;
        Pack n0{}, n1{};
        if (p2 < NP) n0 = load_pack(pole3d, pole2d, mask, 2 * p2 + half, c, cl, active);
        if (p3 < NP) n1 = load_pack(pole3d, pole2d, mask, 2 * p3 + half, c, cl, active);
        consume(c0);
        if (p + NW < NP) consume(c1);
        c0 = n0; c1 = n1;
    }

    // Combine the two halves (within-half lanes hold identical acc)
    const float tot = acc + __shfl_xor(acc, 32);

    // Block partial via LDS
    __shared__ float sh[WPB];
    __shared__ int lastFlag;
    if (lane == 0) sh[tid >> 6] = tot;
    __syncthreads();

    float* partials = ws + 64;   // keep counter in its own cacheline
    if (tid == 0) {
        float bl = 0.f;
        #pragma unroll
        for (int j = 0; j < WPB; ++j) bl += sh[j];
        partials[blockIdx.x] = bl;
        __threadfence();                                   // release partial
        const unsigned prev = atomicAdd((unsigned*)ws, 1u);
        lastFlag = (prev == GRID - 1);
    }
    __syncthreads();

    // Last block reduces all partials (deterministic order)
    if (lastFlag && tid < 64) {
        __threadfence();                                   // acquire
        float s = 0.f;
        for (int i = tid; i < GRID; i += 64) s += partials[i];
        #pragma unroll
        for (int d = 1; d < 64; d <<= 1) s += __shfl_xor(s, d);
        if (tid == 0) out[0] = s * (1.0f / MM);
    }
}

extern "C" void kernel_launch(void* const* d_in, const int* in_sizes, int n_in,
                              void* d_out, int out_size, void* d_ws, size_t ws_size,
                              hipStream_t stream) {
    const float* pole3d = (const float*)d_in[0];
    const float* pole2d = (const float*)d_in[1];
    const float* Kmat   = (const float*)d_in[2];
    const float* dist   = (const float*)d_in[3];
    const float* Rmat   = (const float*)d_in[4];
    const float* tvec   = (const float*)d_in[5];
    // d_in[6] = pole (unused: LINE_W = LENGTH_W = 0)
    const int*   mask   = (const int*)d_in[7];
    float* out = (float*)d_out;
    float* ws  = (float*)d_ws;

    // Zero the last-block counter (ws[0]) every call — deterministic across replays
    hipMemsetAsync(ws, 0, sizeof(unsigned), stream);

    ba_main_kernel<<<GRID, BLK, 0, stream>>>(
        pole3d, pole2d, Kmat, dist, Rmat, tvec, mask, ws, out);
}